// Round 1
// baseline (13215.549 us; speedup 1.0000x reference)
//
#include <hip/hip_runtime.h>

#define H 512
#define NG 2048
#define BATCHN 8192
#define RTILE 32
#define STEPS 60
#define NWG (BATCHN / RTILE)  // 256

// ws layout (byte offsets)
#define WHH_OFF   0u        // 2048*512 bf16 = 2 MB
#define WIHS_OFF  2097152u  // 2 MB
#define WSM_OFF   4194304u  // 32*512 bf16 = 32 KB
#define BSM_OFF   4227072u  // 32 f32
#define S_OFF     8388608u  // 2048*8192 bf16 = 32 MB

typedef short s16x8 __attribute__((ext_vector_type(8)));
typedef float f32x4 __attribute__((ext_vector_type(4)));
typedef float f32x2 __attribute__((ext_vector_type(2)));
typedef unsigned int u32x2 __attribute__((ext_vector_type(2)));

__device__ inline unsigned f2bf(float f) {
  unsigned u = __builtin_bit_cast(unsigned, f);
  return (u + 0x7fffu + ((u >> 16) & 1u)) >> 16;  // RNE, finite inputs
}
__device__ inline float bf2f(unsigned s) {
  return __builtin_bit_cast(float, s << 16);
}
__device__ inline float sigm(float x) {
  float e = __builtin_amdgcn_exp2f(-1.442695041f * x);
  return __builtin_amdgcn_rcpf(1.0f + e);
}
__device__ inline float tanh_(float x) {
  float e = __builtin_amdgcn_exp2f(2.885390082f * x);
  return 1.0f - 2.0f * __builtin_amdgcn_rcpf(1.0f + e);  // safe at +/-inf
}
__device__ inline f32x4 mfma16(s16x8 a, s16x8 b, f32x4 c) {
  return __builtin_amdgcn_mfma_f32_16x16x32_bf16(a, b, c, 0, 0, 0);
}
// swizzled byte address into h_lds: row b (bf16 row of 512), element k
__device__ inline int haddr(int b, int k) {
  return b * 1024 + ((k * 2) ^ ((b & 7) << 4));
}

// ---------------- pack kernel: fp32 weights -> bf16 MFMA-fragment order ----
__global__ void pack_kernel(const float* __restrict__ w_ih, const float* __restrict__ w_hh,
                            const float* __restrict__ w_out, const float* __restrict__ b_out,
                            const float* __restrict__ w_mode, const float* __restrict__ b_mode,
                            unsigned char* __restrict__ ws) {
  unsigned idx = blockIdx.x * 256 + threadIdx.x;
  unsigned short* whh_p  = (unsigned short*)(ws + WHH_OFF);
  unsigned short* wihs_p = (unsigned short*)(ws + WIHS_OFF);
  unsigned short* wsm_p  = (unsigned short*)(ws + WSM_OFF);
  float* bsm = (float*)(ws + BSM_OFF);
  if (idx < 1048576u) {            // w_hh: A[i=n][k], i=lane&15, k=(lane>>4)*8+e
    unsigned e = idx & 7u, lane = (idx >> 3) & 63u, kb = (idx >> 9) & 15u, nb = idx >> 13;
    unsigned n = nb * 16u + (lane & 15u), k = kb * 32u + (lane >> 4) * 8u + e;
    whh_p[idx] = (unsigned short)f2bf(w_hh[n * 512u + k]);
  } else if (idx < 2097152u) {     // w_ih social columns (2..513)
    unsigned j = idx - 1048576u;
    unsigned e = j & 7u, lane = (j >> 3) & 63u, kb = (j >> 9) & 15u, nb = j >> 13;
    unsigned n = nb * 16u + (lane & 15u), k = kb * 32u + (lane >> 4) * 8u + e;
    wihs_p[j] = (unsigned short)f2bf(w_ih[n * 514u + 2u + k]);
  } else if (idx < 2097152u + 16384u) {  // [w_out;w_mode;0] padded to 32 rows
    unsigned j = idx - 2097152u;
    unsigned e = j & 7u, lane = (j >> 3) & 63u, kb = (j >> 9) & 15u, nb = j >> 13;
    unsigned o = nb * 16u + (lane & 15u), k = kb * 32u + (lane >> 4) * 8u + e;
    float v = 0.0f;
    if (o < 12u) v = w_out[o * 512u + k];
    else if (o < 18u) v = w_mode[(o - 12u) * 512u + k];
    wsm_p[j] = (unsigned short)f2bf(v);
  } else if (idx < 2097152u + 16384u + 32u) {
    unsigned o = idx - (2097152u + 16384u);
    float v = 0.0f;
    if (o < 12u) v = b_out[o];
    else if (o < 18u) v = b_mode[o - 12u];
    bsm[o] = v;
  }
}

// ---------------- main kernel: 256 wgs x 512 thr, each wg = 32 batch rows --
__global__ __launch_bounds__(512) void lstm_kernel(
    const float* __restrict__ social, const float* __restrict__ hidden,
    const float* __restrict__ cell, const float* __restrict__ w_ih,
    const float* __restrict__ b_ih, const float* __restrict__ b_hh,
    float* __restrict__ out, unsigned char* __restrict__ ws) {

  const int tid = threadIdx.x;
  const int wid = tid >> 6;    // 0..7
  const int lane = tid & 63;
  const int q = lane >> 4;     // 0..3
  const int r = lane & 15;
  const int wg = blockIdx.x;
  const int gb0 = wg * RTILE;

  const s16x8* whh_p  = (const s16x8*)(ws + WHH_OFF);
  const s16x8* wihs_p = (const s16x8*)(ws + WIHS_OFF);
  const s16x8* wsm_p  = (const s16x8*)(ws + WSM_OFF);
  const float* bsm    = (const float*)(ws + BSM_OFF);
  u32x2* s_pack       = (u32x2*)(ws + S_OFF);

  __shared__ unsigned short h_lds[RTILE * H];  // 32 KB, XOR-swizzled bf16
  __shared__ float wx_lds[NG * 2];             // 16 KB  w_ih[:, 0:2]
  __shared__ float mode_lds[RTILE][8];
  __shared__ float x_lds[RTILE][2];

  // ---- stage social -> h_lds (bf16 swizzled), wx, zero x ----
  #pragma unroll
  for (int i = 0; i < 8; ++i) {
    int rr = i * 4 + (tid >> 7);
    int kk = (tid & 127) * 4;
    f32x4 v = *(const f32x4*)(social + (size_t)(gb0 + rr) * H + kk);
    u32x2 p;
    p[0] = f2bf(v[0]) | (f2bf(v[1]) << 16);
    p[1] = f2bf(v[2]) | (f2bf(v[3]) << 16);
    *(u32x2*)((char*)h_lds + haddr(rr, kk)) = p;
  }
  for (int n = tid; n < NG; n += 512) {
    wx_lds[n * 2 + 0] = w_ih[(size_t)n * 514 + 0];
    wx_lds[n * 2 + 1] = w_ih[(size_t)n * 514 + 1];
  }
  if (tid < RTILE * 2) ((float*)x_lds)[tid] = 0.0f;
  __syncthreads();

  // ---- S phase: S = social @ w_ihS.T + (b_ih+b_hh), store bf16 packed ----
  #pragma unroll
  for (int jb = 0; jb < 4; ++jb) {
    f32x4 acc[4][2];
    #pragma unroll
    for (int g = 0; g < 4; ++g) {
      int n0 = g * 512 + wid * 64 + jb * 16 + q * 4;
      f32x4 bi = *(const f32x4*)(b_ih + n0);
      f32x4 bh = *(const f32x4*)(b_hh + n0);
      f32x4 bias = bi + bh;
      acc[g][0] = bias; acc[g][1] = bias;
    }
    #pragma unroll
    for (int kb = 0; kb < 16; ++kb) {
      s16x8 bfrag[2];
      #pragma unroll
      for (int bb = 0; bb < 2; ++bb)
        bfrag[bb] = *(const s16x8*)((char*)h_lds + haddr(bb * 16 + r, kb * 32 + q * 8));
      #pragma unroll
      for (int g = 0; g < 4; ++g) {
        int nb = g * 32 + wid * 4 + jb;
        s16x8 afrag = wihs_p[(nb * 16 + kb) * 64 + lane];
        acc[g][0] = mfma16(afrag, bfrag[0], acc[g][0]);
        acc[g][1] = mfma16(afrag, bfrag[1], acc[g][1]);
      }
    }
    #pragma unroll
    for (int g = 0; g < 4; ++g) {
      int nb = g * 32 + wid * 4 + jb;
      #pragma unroll
      for (int bb = 0; bb < 2; ++bb) {
        int gbb = wg * 2 + bb;
        u32x2 pk;
        pk[0] = f2bf(acc[g][bb][0]) | (f2bf(acc[g][bb][1]) << 16);
        pk[1] = f2bf(acc[g][bb][2]) | (f2bf(acc[g][bb][3]) << 16);
        __builtin_nontemporal_store(pk, s_pack + (size_t)(nb * 512 + gbb) * 64 + lane);
      }
    }
  }
  __syncthreads();

  // ---- stage h0 (overwrite social in LDS), c0 into registers ----
  #pragma unroll
  for (int i = 0; i < 8; ++i) {
    int rr = i * 4 + (tid >> 7);
    int kk = (tid & 127) * 4;
    f32x4 v = *(const f32x4*)(hidden + (size_t)(gb0 + rr) * H + kk);
    u32x2 p;
    p[0] = f2bf(v[0]) | (f2bf(v[1]) << 16);
    p[1] = f2bf(v[2]) | (f2bf(v[3]) << 16);
    *(u32x2*)((char*)h_lds + haddr(rr, kk)) = p;
  }
  float c_reg[4][2][4];
  #pragma unroll
  for (int jb = 0; jb < 4; ++jb) {
    #pragma unroll
    for (int bb = 0; bb < 2; ++bb) {
      int b = bb * 16 + r;
      int j0 = wid * 64 + jb * 16 + q * 4;
      f32x4 cv = *(const f32x4*)(cell + (size_t)(gb0 + b) * H + j0);
      #pragma unroll
      for (int e = 0; e < 4; ++e) c_reg[jb][bb][e] = cv[e];
    }
  }
  __syncthreads();

  // ---- projection constants (waves 0..3 do phase C) ----
  const int nb_s = (wid >> 1) & 1;
  const int bb_s = wid & 1;
  const int b_s = bb_s * 16 + r;
  const int o0 = nb_s * 16 + q * 4;
  const bool do_c = (wid < 4);
  f32x4 bias_c = *(const f32x4*)(bsm + o0);
  const size_t MODE_BASE = (size_t)BATCHN * 720;

  for (int t = 0; t < STEPS; ++t) {
    // x from previous step (zeros at t=0)
    float xv0[2], xv1[2];
    #pragma unroll
    for (int bb = 0; bb < 2; ++bb) {
      f32x2 xv = *(const f32x2*)(&x_lds[bb * 16 + r][0]);
      xv0[bb] = xv[0]; xv1[bb] = xv[1];
    }
    u32x2 hpend[4][2];
    #pragma unroll
    for (int jb = 0; jb < 4; ++jb) {
      f32x4 acc[4][2];
      // init from S (bf16, fragment-packed)
      #pragma unroll
      for (int g = 0; g < 4; ++g) {
        int nb = g * 32 + wid * 4 + jb;
        #pragma unroll
        for (int bb = 0; bb < 2; ++bb) {
          int gbb = wg * 2 + bb;
          u32x2 sv = __builtin_nontemporal_load(s_pack + (size_t)(nb * 512 + gbb) * 64 + lane);
          f32x4 a;
          a[0] = bf2f(sv[0] & 0xffffu); a[1] = bf2f(sv[0] >> 16);
          a[2] = bf2f(sv[1] & 0xffffu); a[3] = bf2f(sv[1] >> 16);
          acc[g][bb] = a;
        }
      }
      // x @ w_ih[:, :2].T
      #pragma unroll
      for (int g = 0; g < 4; ++g) {
        int n0 = g * 512 + wid * 64 + jb * 16 + q * 4;
        f32x4 wxa = *(const f32x4*)(wx_lds + n0 * 2);
        f32x4 wxb = *(const f32x4*)(wx_lds + n0 * 2 + 4);
        #pragma unroll
        for (int bb = 0; bb < 2; ++bb) {
          acc[g][bb][0] += xv0[bb] * wxa[0] + xv1[bb] * wxa[1];
          acc[g][bb][1] += xv0[bb] * wxa[2] + xv1[bb] * wxa[3];
          acc[g][bb][2] += xv0[bb] * wxb[0] + xv1[bb] * wxb[1];
          acc[g][bb][3] += xv0[bb] * wxb[2] + xv1[bb] * wxb[3];
        }
      }
      // h @ w_hh.T (MFMA over K=512)
      #pragma unroll
      for (int kb = 0; kb < 16; ++kb) {
        s16x8 bfrag[2];
        #pragma unroll
        for (int bb = 0; bb < 2; ++bb)
          bfrag[bb] = *(const s16x8*)((char*)h_lds + haddr(bb * 16 + r, kb * 32 + q * 8));
        #pragma unroll
        for (int g = 0; g < 4; ++g) {
          int nb = g * 32 + wid * 4 + jb;
          s16x8 afrag = whh_p[(nb * 16 + kb) * 64 + lane];
          acc[g][0] = mfma16(afrag, bfrag[0], acc[g][0]);
          acc[g][1] = mfma16(afrag, bfrag[1], acc[g][1]);
        }
      }
      // LSTM cell (c in fp32 regs), h_new -> pending bf16
      #pragma unroll
      for (int bb = 0; bb < 2; ++bb) {
        unsigned hp[4];
        #pragma unroll
        for (int e = 0; e < 4; ++e) {
          float iv = sigm(acc[0][bb][e]);
          float fv = sigm(acc[1][bb][e]);
          float gv = tanh_(acc[2][bb][e]);
          float ov = sigm(acc[3][bb][e]);
          float cn = fv * c_reg[jb][bb][e] + iv * gv;
          c_reg[jb][bb][e] = cn;
          float hn = ov * tanh_(cn);
          hp[e] = f2bf(hn);
        }
        hpend[jb][bb][0] = hp[0] | (hp[1] << 16);
        hpend[jb][bb][1] = hp[2] | (hp[3] << 16);
      }
    }
    __syncthreads();  // all reads of h(t-1) done
    #pragma unroll
    for (int jb = 0; jb < 4; ++jb) {
      #pragma unroll
      for (int bb = 0; bb < 2; ++bb)
        *(u32x2*)((char*)h_lds + haddr(bb * 16 + r, wid * 64 + jb * 16 + q * 4)) = hpend[jb][bb];
    }
    __syncthreads();  // h(t) visible
    // ---- projection: [w_out; w_mode] @ h_new, one MFMA tile per wave ----
    if (do_c) {
      f32x4 pacc = bias_c;
      #pragma unroll
      for (int kb = 0; kb < 16; ++kb) {
        s16x8 bfrag = *(const s16x8*)((char*)h_lds + haddr(b_s, kb * 32 + q * 8));
        s16x8 afrag = wsm_p[(nb_s * 16 + kb) * 64 + lane];
        pacc = mfma16(afrag, bfrag, pacc);
      }
      int b_glob = gb0 + b_s;
      if (o0 < 12) {
        __builtin_nontemporal_store(pacc, (f32x4*)(out + ((size_t)b_glob * 60 + t) * 12 + o0));
        if (o0 == 0) { x_lds[b_s][0] = pacc[0]; x_lds[b_s][1] = pacc[1]; }
      } else if (o0 == 12) {
        *(f32x4*)(&mode_lds[b_s][0]) = pacc;
      } else if (o0 == 16) {
        mode_lds[b_s][4] = pacc[0];
        mode_lds[b_s][5] = pacc[1];
      }
    }
    __syncthreads();  // modes + x(t) visible
    if (tid < RTILE) {
      float v0 = mode_lds[tid][0], v1 = mode_lds[tid][1], v2 = mode_lds[tid][2];
      float v3 = mode_lds[tid][3], v4 = mode_lds[tid][4], v5 = mode_lds[tid][5];
      float mx = fmaxf(fmaxf(fmaxf(v0, v1), fmaxf(v2, v3)), fmaxf(v4, v5));
      float e0 = __builtin_amdgcn_exp2f(1.442695041f * (v0 - mx));
      float e1 = __builtin_amdgcn_exp2f(1.442695041f * (v1 - mx));
      float e2 = __builtin_amdgcn_exp2f(1.442695041f * (v2 - mx));
      float e3 = __builtin_amdgcn_exp2f(1.442695041f * (v3 - mx));
      float e4 = __builtin_amdgcn_exp2f(1.442695041f * (v4 - mx));
      float e5 = __builtin_amdgcn_exp2f(1.442695041f * (v5 - mx));
      float s = e0 + e1 + e2 + e3 + e4 + e5;
      float inv = __builtin_amdgcn_rcpf(s);
      float* mo = out + MODE_BASE + (size_t)(gb0 + tid) * 360 + t * 6;
      mo[0] = e0 * inv; mo[1] = e1 * inv; mo[2] = e2 * inv;
      mo[3] = e3 * inv; mo[4] = e4 * inv; mo[5] = e5 * inv;
    }
  }
}

extern "C" void kernel_launch(void* const* d_in, const int* in_sizes, int n_in,
                              void* d_out, int out_size, void* d_ws, size_t ws_size,
                              hipStream_t stream) {
  const float* social = (const float*)d_in[0];
  const float* hidden = (const float*)d_in[1];
  const float* cell   = (const float*)d_in[2];
  const float* w_ih   = (const float*)d_in[3];
  const float* w_hh   = (const float*)d_in[4];
  const float* b_ih   = (const float*)d_in[5];
  const float* b_hh   = (const float*)d_in[6];
  const float* w_out  = (const float*)d_in[7];
  const float* b_out  = (const float*)d_in[8];
  const float* w_mode = (const float*)d_in[9];
  const float* b_mode = (const float*)d_in[10];
  unsigned char* ws = (unsigned char*)d_ws;
  float* out = (float*)d_out;

  int pack_total = 2097152 + 16384 + 32;
  hipLaunchKernelGGL(pack_kernel, dim3((pack_total + 255) / 256), dim3(256), 0, stream,
                     w_ih, w_hh, w_out, b_out, w_mode, b_mode, ws);
  hipLaunchKernelGGL(lstm_kernel, dim3(NWG), dim3(512), 0, stream,
                     social, hidden, cell, w_ih, b_ih, b_hh, out, ws);
}

// Round 2
// 10074.654 us; speedup vs baseline: 1.3118x; 1.3118x over previous
//
#include <hip/hip_runtime.h>

#define H 512
#define NG 2048
#define BATCHN 8192
#define RTILE 32
#define STEPS 60
#define NWG (BATCHN / RTILE)  // 256

// ws layout (byte offsets)
#define WHH_OFF   0u        // 2048*512 bf16 = 2 MB, MFMA A-fragment order
#define WIHS_OFF  2097152u  // 2 MB
#define WSM_OFF   4194304u  // 32*512 bf16 = 32 KB
#define BSM_OFF   4227072u  // 32 f32

typedef short s16x8 __attribute__((ext_vector_type(8)));
typedef float f32x4 __attribute__((ext_vector_type(4)));
typedef float f32x2 __attribute__((ext_vector_type(2)));
typedef unsigned int u32x2 __attribute__((ext_vector_type(2)));
typedef const void __attribute__((address_space(1))) gas_void;
typedef void __attribute__((address_space(3))) las_void;

__device__ inline unsigned f2bf(float f) {
  unsigned u = __builtin_bit_cast(unsigned, f);
  return (u + 0x7fffu + ((u >> 16) & 1u)) >> 16;  // RNE, finite inputs
}
__device__ inline float bf2f(unsigned s) {
  return __builtin_bit_cast(float, s << 16);
}
__device__ inline float sigm(float x) {
  float e = __builtin_amdgcn_exp2f(-1.442695041f * x);
  return __builtin_amdgcn_rcpf(1.0f + e);
}
__device__ inline float tanh_(float x) {
  float e = __builtin_amdgcn_exp2f(2.885390082f * x);
  return 1.0f - 2.0f * __builtin_amdgcn_rcpf(1.0f + e);
}
__device__ inline f32x4 mfma16(s16x8 a, s16x8 b, f32x4 c) {
  return __builtin_amdgcn_mfma_f32_16x16x32_bf16(a, b, c, 0, 0, 0);
}
// swizzled byte address into h_lds: row b, bf16 element k
__device__ inline int haddr(int b, int k) {
  return b * 1024 + ((k * 2) ^ ((b & 7) << 4));
}

// stage the 4 A-fragments (4 KB) this wave needs for flat iter `flat` into
// ring slot `slot`. LDS dest is wave-uniform; HW appends lane*16.
__device__ inline void stage4(const s16x8* base, int flat, int slot, int wid,
                              int lane, s16x8* wring) {
  int jb = flat >> 4, kb = flat & 15;
  #pragma unroll
  for (int g = 0; g < 4; ++g) {
    int nb = g * 32 + wid * 4 + jb;
    const s16x8* src = base + (size_t)(nb * 16 + kb) * 64 + lane;
    s16x8* dst = &wring[(size_t)((slot * 8 + wid) * 4 + g) * 64];
    __builtin_amdgcn_global_load_lds((gas_void*)src, (las_void*)dst, 16, 0, 0);
  }
}

// ---------------- pack kernel: fp32 weights -> bf16 MFMA-fragment order ----
__global__ void pack_kernel(const float* __restrict__ w_ih, const float* __restrict__ w_hh,
                            const float* __restrict__ w_out, const float* __restrict__ b_out,
                            const float* __restrict__ w_mode, const float* __restrict__ b_mode,
                            unsigned char* __restrict__ ws) {
  unsigned idx = blockIdx.x * 256 + threadIdx.x;
  unsigned short* whh_p  = (unsigned short*)(ws + WHH_OFF);
  unsigned short* wihs_p = (unsigned short*)(ws + WIHS_OFF);
  unsigned short* wsm_p  = (unsigned short*)(ws + WSM_OFF);
  float* bsm = (float*)(ws + BSM_OFF);
  if (idx < 1048576u) {            // w_hh
    unsigned e = idx & 7u, lane = (idx >> 3) & 63u, kb = (idx >> 9) & 15u, nb = idx >> 13;
    unsigned n = nb * 16u + (lane & 15u), k = kb * 32u + (lane >> 4) * 8u + e;
    whh_p[idx] = (unsigned short)f2bf(w_hh[n * 512u + k]);
  } else if (idx < 2097152u) {     // w_ih social columns (2..513)
    unsigned j = idx - 1048576u;
    unsigned e = j & 7u, lane = (j >> 3) & 63u, kb = (j >> 9) & 15u, nb = j >> 13;
    unsigned n = nb * 16u + (lane & 15u), k = kb * 32u + (lane >> 4) * 8u + e;
    wihs_p[j] = (unsigned short)f2bf(w_ih[n * 514u + 2u + k]);
  } else if (idx < 2097152u + 16384u) {  // [w_out;w_mode;0] padded to 32 rows
    unsigned j = idx - 2097152u;
    unsigned e = j & 7u, lane = (j >> 3) & 63u, kb = (j >> 9) & 15u, nb = j >> 13;
    unsigned o = nb * 16u + (lane & 15u), k = kb * 32u + (lane >> 4) * 8u + e;
    float v = 0.0f;
    if (o < 12u) v = w_out[o * 512u + k];
    else if (o < 18u) v = w_mode[(o - 12u) * 512u + k];
    wsm_p[j] = (unsigned short)f2bf(v);
  } else if (idx < 2097152u + 16384u + 32u) {
    unsigned o = idx - (2097152u + 16384u);
    float v = 0.0f;
    if (o < 12u) v = b_out[o];
    else if (o < 18u) v = b_mode[o - 12u];
    bsm[o] = v;
  }
}

// ---------------- main kernel: 256 wgs x 512 thr, each wg = 32 batch rows --
__global__ __launch_bounds__(512, 2) void lstm_kernel(
    const float* __restrict__ social, const float* __restrict__ hidden,
    const float* __restrict__ cell, const float* __restrict__ w_ih,
    const float* __restrict__ b_ih, const float* __restrict__ b_hh,
    float* __restrict__ out, unsigned char* __restrict__ ws) {

  const int tid = threadIdx.x;
  const int wid = tid >> 6;    // 0..7
  const int lane = tid & 63;
  const int q = lane >> 4;     // 0..3
  const int r = lane & 15;
  const int wg = blockIdx.x;
  const int gb0 = wg * RTILE;

  const s16x8* whh_p  = (const s16x8*)(ws + WHH_OFF);
  const s16x8* wihs_p = (const s16x8*)(ws + WIHS_OFF);
  const s16x8* wsm_g  = (const s16x8*)(ws + WSM_OFF);
  const float* bsm    = (const float*)(ws + BSM_OFF);

  __shared__ unsigned short h_lds[RTILE * H];   // 32 KB, XOR-swizzled bf16
  __shared__ s16x8 wring[2 * 8 * 4 * 64];       // 64 KB weight ring (depth 2)
  __shared__ float wx_lds[NG * 2];              // 16 KB  w_ih[:, 0:2]
  __shared__ s16x8 wsm_lds[2 * 16 * 64];        // 32 KB  [w_out;w_mode] frags
  __shared__ float mode_lds[RTILE][8];
  __shared__ float x_lds[RTILE][2];

  // ---- stage social -> h_lds (bf16 swizzled), wx, wsm, zero x ----
  #pragma unroll
  for (int i = 0; i < 8; ++i) {
    int rr = i * 4 + (tid >> 7);
    int kk = (tid & 127) * 4;
    f32x4 v = *(const f32x4*)(social + (size_t)(gb0 + rr) * H + kk);
    u32x2 p;
    p[0] = f2bf(v[0]) | (f2bf(v[1]) << 16);
    p[1] = f2bf(v[2]) | (f2bf(v[3]) << 16);
    *(u32x2*)((char*)h_lds + haddr(rr, kk)) = p;
  }
  for (int n = tid; n < NG; n += 512) {
    wx_lds[n * 2 + 0] = w_ih[(size_t)n * 514 + 0];
    wx_lds[n * 2 + 1] = w_ih[(size_t)n * 514 + 1];
  }
  #pragma unroll
  for (int j = 0; j < 4; ++j) wsm_lds[j * 512 + tid] = wsm_g[j * 512 + tid];
  if (tid < RTILE * 2) ((float*)x_lds)[tid] = 0.0f;
  __syncthreads();

  // ---- S phase: S = social @ w_ihS.T + (b_ih+b_hh) -> s_reg (packed bf16) --
  u32x2 s_reg[4][4][2];
  stage4(wihs_p, 0, 0, wid, lane, wring);
  #pragma unroll
  for (int jb = 0; jb < 4; ++jb) {
    f32x4 acc[4][2];
    #pragma unroll
    for (int g = 0; g < 4; ++g) {
      int n0 = g * 512 + wid * 64 + jb * 16 + q * 4;
      f32x4 bi = *(const f32x4*)(b_ih + n0);
      f32x4 bh = *(const f32x4*)(b_hh + n0);
      f32x4 bias = bi + bh;
      acc[g][0] = bias; acc[g][1] = bias;
    }
    #pragma unroll
    for (int kb = 0; kb < 16; ++kb) {
      int F = jb * 16 + kb;
      if (F < 63) stage4(wihs_p, F + 1, (F + 1) & 1, wid, lane, wring);
      else        stage4(whh_p, 0, 0, wid, lane, wring);  // prefetch t=0
      asm volatile("s_waitcnt vmcnt(4)" ::: "memory");
      int slot = F & 1;
      s16x8 bfrag[2];
      #pragma unroll
      for (int bb = 0; bb < 2; ++bb)
        bfrag[bb] = *(const s16x8*)((char*)h_lds + haddr(bb * 16 + r, kb * 32 + q * 8));
      #pragma unroll
      for (int g = 0; g < 4; ++g) {
        s16x8 af = wring[(size_t)((slot * 8 + wid) * 4 + g) * 64 + lane];
        acc[g][0] = mfma16(af, bfrag[0], acc[g][0]);
        acc[g][1] = mfma16(af, bfrag[1], acc[g][1]);
      }
    }
    #pragma unroll
    for (int g = 0; g < 4; ++g) {
      #pragma unroll
      for (int bb = 0; bb < 2; ++bb) {
        s_reg[jb][g][bb][0] = f2bf(acc[g][bb][0]) | (f2bf(acc[g][bb][1]) << 16);
        s_reg[jb][g][bb][1] = f2bf(acc[g][bb][2]) | (f2bf(acc[g][bb][3]) << 16);
      }
    }
  }
  __syncthreads();

  // ---- stage h0 (overwrite social in LDS), c0 into registers ----
  #pragma unroll
  for (int i = 0; i < 8; ++i) {
    int rr = i * 4 + (tid >> 7);
    int kk = (tid & 127) * 4;
    f32x4 v = *(const f32x4*)(hidden + (size_t)(gb0 + rr) * H + kk);
    u32x2 p;
    p[0] = f2bf(v[0]) | (f2bf(v[1]) << 16);
    p[1] = f2bf(v[2]) | (f2bf(v[3]) << 16);
    *(u32x2*)((char*)h_lds + haddr(rr, kk)) = p;
  }
  float c_reg[4][2][4];
  #pragma unroll
  for (int jb = 0; jb < 4; ++jb) {
    #pragma unroll
    for (int bb = 0; bb < 2; ++bb) {
      int b = bb * 16 + r;
      int j0 = wid * 64 + jb * 16 + q * 4;
      f32x4 cv = *(const f32x4*)(cell + (size_t)(gb0 + b) * H + j0);
      #pragma unroll
      for (int e = 0; e < 4; ++e) c_reg[jb][bb][e] = cv[e];
    }
  }
  __syncthreads();

  // ---- projection constants (waves 0..3 do projection) ----
  const int nb_s = (wid >> 1) & 1;
  const int bb_s = wid & 1;
  const int b_s = bb_s * 16 + r;
  const int o0 = nb_s * 16 + q * 4;
  const bool do_c = (wid < 4);
  f32x4 bias_c = *(const f32x4*)(bsm + o0);
  const size_t MODE_BASE = (size_t)BATCHN * 720;

  for (int t = 0; t < STEPS; ++t) {
    float xv0[2], xv1[2];
    #pragma unroll
    for (int bb = 0; bb < 2; ++bb) {
      f32x2 xv = *(const f32x2*)(&x_lds[bb * 16 + r][0]);
      xv0[bb] = xv[0]; xv1[bb] = xv[1];
    }
    u32x2 hpend[4][2];
    #pragma unroll
    for (int jb = 0; jb < 4; ++jb) {
      f32x4 acc[4][2];
      // init from S (registers) + x @ w_ih[:, :2].T
      #pragma unroll
      for (int g = 0; g < 4; ++g) {
        int n0 = g * 512 + wid * 64 + jb * 16 + q * 4;
        f32x4 wxa = *(const f32x4*)(wx_lds + n0 * 2);
        f32x4 wxb = *(const f32x4*)(wx_lds + n0 * 2 + 4);
        #pragma unroll
        for (int bb = 0; bb < 2; ++bb) {
          u32x2 sv = s_reg[jb][g][bb];
          f32x4 a;
          a[0] = bf2f(sv[0] & 0xffffu); a[1] = bf2f(sv[0] >> 16);
          a[2] = bf2f(sv[1] & 0xffffu); a[3] = bf2f(sv[1] >> 16);
          a[0] += xv0[bb] * wxa[0] + xv1[bb] * wxa[1];
          a[1] += xv0[bb] * wxa[2] + xv1[bb] * wxa[3];
          a[2] += xv0[bb] * wxb[0] + xv1[bb] * wxb[1];
          a[3] += xv0[bb] * wxb[2] + xv1[bb] * wxb[3];
          acc[g][bb] = a;
        }
      }
      // h @ w_hh.T : MFMA over K=512, weights via LDS ring (prefetch d=1)
      #pragma unroll
      for (int kb = 0; kb < 16; ++kb) {
        int F = jb * 16 + kb;
        bool last = (t == STEPS - 1) && (F == 63);
        if (F < 63)           stage4(whh_p, F + 1, (F + 1) & 1, wid, lane, wring);
        else if (t < STEPS-1) stage4(whh_p, 0, 0, wid, lane, wring);
        if (!last) asm volatile("s_waitcnt vmcnt(4)" ::: "memory");
        else       asm volatile("s_waitcnt vmcnt(0)" ::: "memory");
        int slot = F & 1;
        s16x8 bfrag[2];
        #pragma unroll
        for (int bb = 0; bb < 2; ++bb)
          bfrag[bb] = *(const s16x8*)((char*)h_lds + haddr(bb * 16 + r, kb * 32 + q * 8));
        #pragma unroll
        for (int g = 0; g < 4; ++g) {
          s16x8 af = wring[(size_t)((slot * 8 + wid) * 4 + g) * 64 + lane];
          acc[g][0] = mfma16(af, bfrag[0], acc[g][0]);
          acc[g][1] = mfma16(af, bfrag[1], acc[g][1]);
        }
      }
      // LSTM cell (c in fp32 regs), h_new -> pending bf16
      #pragma unroll
      for (int bb = 0; bb < 2; ++bb) {
        unsigned hp[4];
        #pragma unroll
        for (int e = 0; e < 4; ++e) {
          float iv = sigm(acc[0][bb][e]);
          float fv = sigm(acc[1][bb][e]);
          float gv = tanh_(acc[2][bb][e]);
          float ov = sigm(acc[3][bb][e]);
          float cn = fv * c_reg[jb][bb][e] + iv * gv;
          c_reg[jb][bb][e] = cn;
          float hn = ov * tanh_(cn);
          hp[e] = f2bf(hn);
        }
        hpend[jb][bb][0] = hp[0] | (hp[1] << 16);
        hpend[jb][bb][1] = hp[2] | (hp[3] << 16);
      }
    }
    __syncthreads();  // all reads of h(t-1) done
    #pragma unroll
    for (int jb = 0; jb < 4; ++jb) {
      #pragma unroll
      for (int bb = 0; bb < 2; ++bb)
        *(u32x2*)((char*)h_lds + haddr(bb * 16 + r, wid * 64 + jb * 16 + q * 4)) = hpend[jb][bb];
    }
    __syncthreads();  // h(t) visible
    // ---- projection: [w_out; w_mode] @ h_new, one MFMA tile per wave ----
    if (do_c) {
      f32x4 pacc = bias_c;
      #pragma unroll
      for (int kb = 0; kb < 16; ++kb) {
        s16x8 bfrag = *(const s16x8*)((char*)h_lds + haddr(b_s, kb * 32 + q * 8));
        s16x8 afrag = wsm_lds[(nb_s * 16 + kb) * 64 + lane];
        pacc = mfma16(afrag, bfrag, pacc);
      }
      int b_glob = gb0 + b_s;
      if (o0 < 12) {
        __builtin_nontemporal_store(pacc, (f32x4*)(out + ((size_t)b_glob * 60 + t) * 12 + o0));
        if (o0 == 0) { x_lds[b_s][0] = pacc[0]; x_lds[b_s][1] = pacc[1]; }
      } else if (o0 == 12) {
        *(f32x4*)(&mode_lds[b_s][0]) = pacc;
      } else if (o0 == 16) {
        mode_lds[b_s][4] = pacc[0];
        mode_lds[b_s][5] = pacc[1];
      }
    }
    __syncthreads();  // modes + x(t) visible
    if (tid < RTILE) {
      float v0 = mode_lds[tid][0], v1 = mode_lds[tid][1], v2 = mode_lds[tid][2];
      float v3 = mode_lds[tid][3], v4 = mode_lds[tid][4], v5 = mode_lds[tid][5];
      float mx = fmaxf(fmaxf(fmaxf(v0, v1), fmaxf(v2, v3)), fmaxf(v4, v5));
      float e0 = __builtin_amdgcn_exp2f(1.442695041f * (v0 - mx));
      float e1 = __builtin_amdgcn_exp2f(1.442695041f * (v1 - mx));
      float e2 = __builtin_amdgcn_exp2f(1.442695041f * (v2 - mx));
      float e3 = __builtin_amdgcn_exp2f(1.442695041f * (v3 - mx));
      float e4 = __builtin_amdgcn_exp2f(1.442695041f * (v4 - mx));
      float e5 = __builtin_amdgcn_exp2f(1.442695041f * (v5 - mx));
      float s = e0 + e1 + e2 + e3 + e4 + e5;
      float inv = __builtin_amdgcn_rcpf(s);
      float* mo = out + MODE_BASE + (size_t)(gb0 + tid) * 360 + t * 6;
      mo[0] = e0 * inv; mo[1] = e1 * inv; mo[2] = e2 * inv;
      mo[3] = e3 * inv; mo[4] = e4 * inv; mo[5] = e5 * inv;
    }
  }
}

extern "C" void kernel_launch(void* const* d_in, const int* in_sizes, int n_in,
                              void* d_out, int out_size, void* d_ws, size_t ws_size,
                              hipStream_t stream) {
  const float* social = (const float*)d_in[0];
  const float* hidden = (const float*)d_in[1];
  const float* cell   = (const float*)d_in[2];
  const float* w_ih   = (const float*)d_in[3];
  const float* w_hh   = (const float*)d_in[4];
  const float* b_ih   = (const float*)d_in[5];
  const float* b_hh   = (const float*)d_in[6];
  const float* w_out  = (const float*)d_in[7];
  const float* b_out  = (const float*)d_in[8];
  const float* w_mode = (const float*)d_in[9];
  const float* b_mode = (const float*)d_in[10];
  unsigned char* ws = (unsigned char*)d_ws;
  float* out = (float*)d_out;

  int pack_total = 2097152 + 16384 + 32;
  hipLaunchKernelGGL(pack_kernel, dim3((pack_total + 255) / 256), dim3(256), 0, stream,
                     w_ih, w_hh, w_out, b_out, w_mode, b_mode, ws);
  hipLaunchKernelGGL(lstm_kernel, dim3(NWG), dim3(512), 0, stream,
                     social, hidden, cell, w_ih, b_ih, b_hh, out, ws);
}